// Round 11
// baseline (154.942 us; speedup 1.0000x reference)
//
#include <hip/hip_runtime.h>
#include <math.h>

#define N_    16
#define C_    256
#define H_    56
#define W_    56
#define HW_   3136          // H_*W_
#define NPIX  50176         // N_*HW_
#define OUTC  512
#define SPAN_ 2304          // C_*9
#define BLKPX 256           // conv block pixel tile
#define HBYTES 24576        // one halo buffer: 384 slots * 64 B
#define ZSLOT 24512         // byte offset of zero slot (slot 383) in a buffer
#define PXB3  128           // prep3 pixel tile
#define NPB3  (NPIX / PXB3) // 392 prep3 pixel blocks

typedef unsigned short u16;
typedef unsigned int   u32;
typedef __attribute__((ext_vector_type(8))) short bf16x8;
typedef __attribute__((ext_vector_type(8))) unsigned short u16x8;
typedef __attribute__((ext_vector_type(4))) float f32x4;

__device__ __forceinline__ u16 f2bf(float v) {
    u32 x = __float_as_uint(v);
    u32 r = (x + 0x7fffu + ((x >> 16) & 1u)) >> 16;   // RNE
    return (u16)r;
}

__device__ __forceinline__ int bucketf(float v, float b) {
    int idx = (int)floorf((v + b) / 2.5f);
    int r = idx % 8;
    return r < 0 ? -r : r;
}

// ---- Kernel 1: prep3 -- transpose/convert + tap maps + kbucket + zero -------
// grid = NPB3 + 4. Pixel blocks: 512 threads = 4 channel-groups x 128 px; each
// thread owns 64 channels of one px (pg/ps in regs), writes xp directly as
// u16x8 (no LDS transpose), one LDS reduction pass. 4 tail blocks: kbucket.
__global__ __launch_bounds__(512) void prep3(const float* __restrict__ x,
                                             const float* __restrict__ ah,
                                             const float* __restrict__ bh,
                                             const float* __restrict__ kern,
                                             u16* __restrict__ xp,
                                             float* __restrict__ g,
                                             float* __restrict__ s2,
                                             int* __restrict__ kbuck,
                                             int* __restrict__ counts) {
    int kb = blockIdx.x - NPB3;
    int t = threadIdx.x;
    if (kb >= 0) {
        // ---- kbucket: 128 oc per block, 4 threads per oc ----
        if (kb == 0 && t < 8) counts[t] = 0;
        int oc_l = t >> 2, part = t & 3;
        int oc = kb * 128 + oc_l;
        const float* kr = kern + (size_t)oc * SPAN_ + part * 576;
        const float* ap = ah + part * 576;
        float dot = 0.f, ss = 0.f;
        for (int i = 0; i < 144; ++i) {
            float4 kv = *(const float4*)(kr + i * 4);
            float4 av = *(const float4*)(ap + i * 4);
            dot += kv.x * av.x + kv.y * av.y + kv.z * av.z + kv.w * av.w;
            ss  += kv.x * kv.x + kv.y * kv.y + kv.z * kv.z + kv.w * kv.w;
        }
        dot += __shfl_xor(dot, 1); dot += __shfl_xor(dot, 2);
        ss  += __shfl_xor(ss, 1);  ss  += __shfl_xor(ss, 2);
        if (part == 0) {
            float n2 = ss;            // ||k||^2
            float n4 = n2 * n2;
            float n8 = n4 * n4;
            float v = dot + n2 * ah[SPAN_] + n4 * ah[SPAN_ + 1] +
                      n8 * ah[SPAN_ + 2];
            kbuck[oc] = bucketf(v, bh[0]);
        }
        return;
    }

    __shared__ float aL[SPAN_];          // 9216 B
    __shared__ float red[3][PXB3][10];   // 15360 B
    for (int j = t; j < SPAN_; j += 512) aL[j] = ah[j];

    const int px_l = t & 127;
    const int grp  = t >> 7;             // 0..3 -> channels grp*64..+63
    const int px   = blockIdx.x * PXB3 + px_l;
    const int img  = px / HW_;
    const size_t xbase = (size_t)img * C_ * HW_ + (px - img * HW_);
    const int c0 = grp * 64;

    float pg[9];
#pragma unroll
    for (int kk = 0; kk < 9; ++kk) pg[kk] = 0.f;
    float ps = 0.f;
    __syncthreads();

#pragma unroll
    for (int bt = 0; bt < 4; ++bt) {     // 4 batches of 16 channels
        float R[16];
#pragma unroll
        for (int i = 0; i < 16; ++i)
            R[i] = x[xbase + (size_t)(c0 + bt * 16 + i) * HW_];
        u16x8 pa, pb;
#pragma unroll
        for (int i = 0; i < 16; ++i) {
            float v = R[i];
            const float* ac = &aL[(c0 + bt * 16 + i) * 9];
#pragma unroll
            for (int kk = 0; kk < 9; ++kk) pg[kk] += ac[kk] * v;
            ps += v * v;
            if (i < 8) pa[i] = f2bf(v); else pb[i - 8] = f2bf(v);
        }
        *(u16x8*)&xp[(size_t)px * C_ + c0 + bt * 16]     = pa;
        *(u16x8*)&xp[(size_t)px * C_ + c0 + bt * 16 + 8] = pb;
    }

    if (grp > 0) {
#pragma unroll
        for (int kk = 0; kk < 9; ++kk) red[grp - 1][px_l][kk] = pg[kk];
        red[grp - 1][px_l][9] = ps;
    }
    __syncthreads();
    if (grp == 0) {
#pragma unroll
        for (int kk = 0; kk < 9; ++kk) {
            float s = pg[kk] + red[0][px_l][kk] + red[1][px_l][kk] +
                      red[2][px_l][kk];
            g[(size_t)kk * NPIX + px] = s;
        }
        s2[px] = ps + red[0][px_l][9] + red[1][px_l][9] + red[2][px_l][9];
    }
}

// ---- Kernel B2: per-column vote -> histogram --------------------------------
__global__ __launch_bounds__(256) void vote_kernel(const float* __restrict__ g,
                                                   const float* __restrict__ s2,
                                                   const float* __restrict__ ah,
                                                   const float* __restrict__ bh,
                                                   int* __restrict__ counts) {
    __shared__ int hist[8];
    if (threadIdx.x < 8) hist[threadIdx.x] = 0;
    __syncthreads();
    int q = blockIdx.x * 256 + threadIdx.x;
    int n = q / HW_;
    int p = q - n * HW_;
    int h = p / W_;
    int w = p - h * W_;
    float dot = 0.f, ss = 0.f;
#pragma unroll
    for (int kk = 0; kk < 9; ++kk) {
        int dh = kk / 3 - 1, dw = kk % 3 - 1;
        int hh = h + dh, ww = w + dw;
        if (hh >= 0 && hh < H_ && ww >= 0 && ww < W_) {
            int idx = n * HW_ + hh * W_ + ww;
            dot += g[(size_t)kk * NPIX + idx];
            ss  += s2[idx];
        }
    }
    float qext = 0.5f * (ah[SPAN_] + ah[SPAN_ + 1] + ah[SPAN_ + 2]);
    float v = dot / sqrtf(ss) + qext;
    int b = bucketf(v, bh[0]);
    atomicAdd(&hist[b], 1);
    __syncthreads();
    if (threadIdx.x < 8) atomicAdd(&counts[threadIdx.x], hist[threadIdx.x]);
}

// ---- Kernel P2: self-selecting weight fragmentation -------------------------
__global__ __launch_bounds__(256) void prep_w(const float* __restrict__ kern,
                                              const int* __restrict__ kbuck,
                                              const int* __restrict__ counts,
                                              const int* __restrict__ mode,
                                              float* __restrict__ out,
                                              u16* __restrict__ wfrag,
                                              int nfB, int oc_total) {
    __shared__ int sc[256];
    __shared__ int rowsL[512];
    int t = threadIdx.x;
    int best = 0, bc = counts[0];
#pragma unroll
    for (int i = 1; i < 8; ++i) {
        int c = counts[i];
        if (c > bc) { bc = c; best = i; }   // first max wins
    }
    int f0 = (kbuck[t] == best) ? 1 : 0;
    int f1 = (kbuck[t + 256] == best) ? 1 : 0;
    sc[t] = f0 | (f1 << 16);
    __syncthreads();
    for (int off = 1; off < 256; off <<= 1) {
        int add = (t >= off) ? sc[t - off] : 0;
        __syncthreads();
        sc[t] += add;
        __syncthreads();
    }
    int tot = sc[255];
    int t0  = tot & 0xffff;
    int cnt = t0 + (tot >> 16);
    int pos0 = (sc[t] & 0xffff) - f0;
    int pos1 = t0 + (sc[t] >> 16) - f1;
    rowsL[t] = 0; rowsL[t + 256] = 0;
    __syncthreads();
    if (cnt == 0) { rowsL[t] = t; rowsL[t + 256] = t + 256; }
    else {
        if (f0) rowsL[pos0] = t;
        if (f1) rowsL[pos1] = t + 256;
    }
    __syncthreads();
    int ocEff = (cnt == 0) ? OUTC : cnt;
    float scale = (mode[0] && cnt > 0) ? 512.0f / (float)cnt : 1.0f;

    if (blockIdx.x == 0) {                       // rows output (read as f32)
        float* rout = out + (size_t)N_ * oc_total * HW_;
        int nw = ocEff < oc_total ? ocEff : oc_total;
        if (cnt == 0) {
            if (t < nw) rout[t] = (float)t;
            if (t + 256 < nw) rout[t + 256] = (float)(t + 256);
        } else {
            if (f0 && pos0 < nw) rout[pos0] = (float)t;
            if (f1 && pos1 < nw) rout[pos1] = (float)(t + 256);
        }
    }

    // fragmentation: wfrag elem offset ((s*nfB + g)*64 + lane)*8, K = kk*256+c
    int e = blockIdx.x * 256 + t;
    int lane = e & 63;
    int t2 = e >> 6;
    int g = t2 % nfB;
    int s = t2 / nfB;                    // 0..71
    int kk = s >> 3;
    int cb = s & 7;
    int q = lane >> 4;
    int mcol = lane & 15;
    int oc_i = g * 16 + mcol;
    bool valid = oc_i < ocEff;
    int row = valid ? rowsL[oc_i] : 0;
    const float* kr = kern + (size_t)row * SPAN_;
    u16 w8[8];
#pragma unroll
    for (int j = 0; j < 8; ++j) {
        int c = cb * 32 + q * 8 + j;
        float v = valid ? kr[c * 9 + kk] * scale : 0.f;
        w8[j] = f2bf(v);
    }
    u16* dst = wfrag + ((size_t)((s * nfB + g) * 64 + lane)) * 8;
#pragma unroll
    for (int j = 0; j < 8; ++j) dst[j] = w8[j];
}

// ---- Kernel D: MFMA implicit-GEMM conv --------------------------------------
// 4 waves/block, block tile 256 px x 48 oc. A staged via global_load_lds into a
// double-buffered quarter-XOR-swizzled LDS halo; invalid taps read a dedicated
// zeroed slot via 36 precomputed addresses (zero inner-loop VALU); B register-
// pipelined TWO kk ahead (static 3-slot ring), continuous across the cb seam.
__global__ __launch_bounds__(256, 2) void conv_mfma(const u16* __restrict__ xp,
                                                    const u16* __restrict__ wfrag,
                                                    float* __restrict__ out,
                                                    int nfB, int oc_total, int nby) {
    __shared__ char halo[2 * HBYTES];              // 49152 B

    // XCD swizzle: oc-sibling blocks co-located on one XCD; 196 bx = 24*8 + 4.
    int flat = blockIdx.x;
    int bx, by;
    int full = 192 * nby;
    if (flat < full) {
        int gsz = 8 * nby;
        int gi = flat / gsz;
        int tr = flat - gi * gsz;
        by = tr >> 3;
        bx = gi * 8 + (tr & 7);
    } else {
        int tr = flat - full;
        by = tr >> 2;
        bx = 192 + (tr & 3);
    }

    const int t = threadIdx.x;
    const int lane = t & 63;
    const int wv = t >> 6;                         // 0..3
    const int pb = bx * BLKPX;
    const int fb = by * 3;
    const int lane15 = lane & 15;
    const int laneq  = lane >> 4;

    // zero slot 383 of both buffers (never staged; read target for invalid taps)
    if (t < 8) {
        int off = ((t & 4) ? HBYTES : 0) + ZSLOT + (t & 3) * 16;
        *(u16x8*)&halo[off] = (u16x8){0, 0, 0, 0, 0, 0, 0, 0};
    }

    // 36 precomputed ds_read addresses: validity folded (invalid -> zero slot,
    // pre-subtracting the per-kk immediate so addr+IMM lands on slot 383).
    int addrA[4][9];
#pragma unroll
    for (int f = 0; f < 4; ++f) {
        int p = pb + wv * 64 + f * 16 + lane15;
        int img = p / HW_;
        int rp = p - img * HW_;
        int h = rp / W_;
        int w = rp - h * W_;
#pragma unroll
        for (int kk = 0; kk < 9; ++kk) {
            int dh = kk / 3 - 1, dw = kk % 3 - 1;
            int hh = h + dh, ww = w + dw;
            bool val = (hh >= 0) & (hh < H_) & (ww >= 0) & (ww < W_);
            int sn = 57 + wv * 64 + f * 16 + lane15 + dw;
            int base = sn * 64 + ((laneq ^ ((sn >> 1) & 3)) << 4) - 3584;
            addrA[f][kk] = val ? base : (ZSLOT - (kk / 3) * 3584);
        }
    }

    f32x4 acc[4][3];
#pragma unroll
    for (int f = 0; f < 4; ++f)
#pragma unroll
        for (int gg = 0; gg < 3; ++gg) acc[f][gg] = (f32x4){0.f, 0.f, 0.f, 0.f};

    // staging: 6 global_load_lds_dwordx4/thread; LDS dest linear t*16;
    // global source quarter pre-swizzled: q' = (t&3) ^ ((t>>3)&3).
    // r=5, t>=252 skipped so slot 383 stays zero.
    const char* xpb = (const char*)xp;
    const int q4 = (((t & 3) ^ ((t >> 3) & 3)) << 4);
    int gpx[6];
#pragma unroll
    for (int r = 0; r < 6; ++r) {
        int p = pb - 57 + r * 64 + (t >> 2);
        gpx[r] = p < 0 ? 0 : (p >= NPIX ? NPIX - 1 : p);
    }

#pragma unroll
    for (int r = 0; r < 6; ++r) {
        if (r < 5 || t < 252)
            __builtin_amdgcn_global_load_lds(
                (const __attribute__((address_space(1))) unsigned int*)
                    (xpb + (size_t)gpx[r] * 512 + q4),
                (__attribute__((address_space(3))) unsigned int*)
                    &halo[r * 4096 + t * 16],
                16, 0, 0);
    }

    const size_t cbStride = (size_t)nfB * 512;
    const size_t kkStride = cbStride * 8;
    const u16* wl = wfrag + (size_t)fb * 512 + (size_t)lane * 8;
    bf16x8 bB[3][3];                               // 3-slot ring, distance 2
#define LOADB(slot, cb_, kk_) do {                                              \
    const u16* _wp = wl + (size_t)(kk_) * kkStride + (size_t)(cb_) * cbStride;  \
    _Pragma("unroll")                                                           \
    for (int _g = 0; _g < 3; ++_g)                                              \
        bB[slot][_g] = *(const bf16x8*)(_wp + (size_t)_g * 512);                \
} while (0)

    LOADB(0, 0, 0);
    LOADB(1, 0, 1);

#pragma unroll
    for (int cb = 0; cb < 8; ++cb) {
        __syncthreads();                           // buf[cb&1] ready

        if (cb < 7) {                              // stage next cb, other buf
            const int nb = ((cb + 1) & 1) * HBYTES;
#pragma unroll
            for (int r = 0; r < 6; ++r) {
                if (r < 5 || t < 252)
                    __builtin_amdgcn_global_load_lds(
                        (const __attribute__((address_space(1))) unsigned int*)
                            (xpb + (size_t)gpx[r] * 512 + (cb + 1) * 64 + q4),
                        (__attribute__((address_space(3))) unsigned int*)
                            &halo[nb + r * 4096 + t * 16],
                        16, 0, 0);
            }
        }

#pragma unroll
        for (int kk = 0; kk < 9; ++kk) {
            // B prefetch distance 2, continuous across the cb seam
            if (kk < 7)       LOADB((kk + 2) % 3, cb, kk + 2);
            else if (cb < 7)  LOADB((kk + 2) % 3, cb + 1, kk - 7);

            const int IMM = (cb & 1) * HBYTES + (kk / 3) * 3584;  // compile-time
            bf16x8 aX[4];
#pragma unroll
            for (int f = 0; f < 4; ++f)
                aX[f] = *(const bf16x8*)&halo[addrA[f][kk] + IMM];
#pragma unroll
            for (int gg = 0; gg < 3; ++gg)
#pragma unroll
                for (int f = 0; f < 4; ++f)
                    acc[f][gg] = __builtin_amdgcn_mfma_f32_16x16x32_bf16(
                        aX[f], bB[kk % 3][gg], acc[f][gg], 0, 0, 0);
        }
    }
#undef LOADB

    // epilogue: D row (pixel) = (lane>>4)*4 + r, col (oc) = lane&15
#pragma unroll
    for (int f = 0; f < 4; ++f) {
        int p0 = pb + wv * 64 + f * 16 + laneq * 4;
        int img0 = p0 / HW_;
        int hw0 = p0 - img0 * HW_;
#pragma unroll
        for (int gg = 0; gg < 3; ++gg) {
            int oc = (fb + gg) * 16 + lane15;
            if (oc < oc_total) {
                float* op = out + ((size_t)img0 * oc_total + oc) * HW_ + hw0;
                *(f32x4*)op = acc[f][gg];
            }
        }
    }
}

extern "C" void kernel_launch(void* const* d_in, const int* in_sizes, int n_in,
                              void* d_out, int out_size, void* d_ws, size_t ws_size,
                              hipStream_t stream) {
    const float* x    = (const float*)d_in[0];
    const float* kern = (const float*)d_in[1];
    const float* ah   = (const float*)d_in[2];
    const float* bh   = (const float*)d_in[3];
    const int*   mode = (const int*)d_in[4];
    float* out = (float*)d_out;

    // oc is data-dependent but recoverable from out_size: oc*(16*3136+1)
    int oc_total = (out_size % (N_ * HW_ + 1) == 0) ? out_size / (N_ * HW_ + 1)
                                                    : OUTC;
    int nfTot = (oc_total + 15) / 16;
    int nby   = (nfTot + 2) / 3;             // 3 fragments (48 oc) per block
    int nfB   = nby * 3;

    // workspace layout (sized for worst case nfB = 36)
    u16*   xp     = (u16*)d_ws;                                  // NPIX*256
    u16*   wfrag  = xp + (size_t)NPIX * C_;                      // 72*36*64*8
    float* g      = (float*)(wfrag + (size_t)72 * 36 * 64 * 8);  // 9*NPIX
    float* s2     = g + (size_t)9 * NPIX;                        // NPIX
    int*   counts = (int*)(s2 + NPIX);                           // 8
    int*   kbuck  = counts + 8;                                  // 512

    prep3<<<NPB3 + 4, 512, 0, stream>>>(x, ah, bh, kern, xp, g, s2, kbuck,
                                        counts);
    vote_kernel<<<NPIX / 256, 256, 0, stream>>>(g, s2, ah, bh, counts);
    prep_w<<<18 * nfB, 256, 0, stream>>>(kern, kbuck, counts, mode, out, wfrag,
                                         nfB, oc_total);
    conv_mfma<<<(NPIX / BLKPX) * nby, 256, 0, stream>>>(xp, wfrag, out, nfB,
                                                        oc_total, nby);
}

// Round 12
// 149.563 us; speedup vs baseline: 1.0360x; 1.0360x over previous
//
#include <hip/hip_runtime.h>
#include <math.h>

#define N_    16
#define C_    256
#define H_    56
#define W_    56
#define HW_   3136          // H_*W_
#define NPIX  50176         // N_*HW_
#define OUTC  512
#define SPAN_ 2304          // C_*9
#define BLKPX 256           // conv block pixel tile
#define HBYTES 24576        // one halo buffer: 384 slots * 64 B
#define ZSLOT 24512         // byte offset of zero slot (slot 383) in a buffer
#define PXB4  128           // prep4 pixel tile
#define NPB4  (NPIX / PXB4) // 392 prep4 pixel blocks

typedef unsigned short u16;
typedef unsigned int   u32;
typedef __attribute__((ext_vector_type(8))) short bf16x8;
typedef __attribute__((ext_vector_type(8))) unsigned short u16x8;
typedef __attribute__((ext_vector_type(4))) unsigned short u16x4;
typedef __attribute__((ext_vector_type(4))) float f32x4;

__device__ __forceinline__ u16 f2bf(float v) {
    u32 x = __float_as_uint(v);
    u32 r = (x + 0x7fffu + ((x >> 16) & 1u)) >> 16;   // RNE
    return (u16)r;
}

__device__ __forceinline__ int bucketf(float v, float b) {
    int idx = (int)floorf((v + b) / 2.5f);
    int r = idx % 8;
    return r < 0 ? -r : r;
}

// ---- Kernel 1: prep4 -- transpose/convert + tap maps + kbucket + zero -------
// grid = NPB4 + 4. Pixel blocks: 512 threads = 4 channel-groups x 128 px; each
// thread owns 64 channels of one px (16 per phase), pg/ps in registers; per
// phase the 64-ch slab goes through an LDS transpose tile so xp stores are
// contiguous 128-B-per-pixel segments (prep2's verified coalescing pattern).
// 4 tail blocks: kbucket (128 oc each); tail block 0 zeroes counts.
__global__ __launch_bounds__(512) void prep4(const float* __restrict__ x,
                                             const float* __restrict__ ah,
                                             const float* __restrict__ bh,
                                             const float* __restrict__ kern,
                                             u16* __restrict__ xp,
                                             float* __restrict__ g,
                                             float* __restrict__ s2,
                                             int* __restrict__ kbuck,
                                             int* __restrict__ counts) {
    int kb = blockIdx.x - NPB4;
    int t = threadIdx.x;
    if (kb >= 0) {
        // ---- kbucket: 128 oc per block, 4 threads per oc ----
        if (kb == 0 && t < 8) counts[t] = 0;
        int oc_l = t >> 2, part = t & 3;
        int oc = kb * 128 + oc_l;
        const float* kr = kern + (size_t)oc * SPAN_ + part * 576;
        const float* ap = ah + part * 576;
        float dot = 0.f, ss = 0.f;
        for (int i = 0; i < 144; ++i) {
            float4 kv = *(const float4*)(kr + i * 4);
            float4 av = *(const float4*)(ap + i * 4);
            dot += kv.x * av.x + kv.y * av.y + kv.z * av.z + kv.w * av.w;
            ss  += kv.x * kv.x + kv.y * kv.y + kv.z * kv.z + kv.w * kv.w;
        }
        dot += __shfl_xor(dot, 1); dot += __shfl_xor(dot, 2);
        ss  += __shfl_xor(ss, 1);  ss  += __shfl_xor(ss, 2);
        if (part == 0) {
            float n2 = ss;            // ||k||^2
            float n4 = n2 * n2;
            float n8 = n4 * n4;
            float v = dot + n2 * ah[SPAN_] + n4 * ah[SPAN_ + 1] +
                      n8 * ah[SPAN_ + 2];
            kbuck[oc] = bucketf(v, bh[0]);
        }
        return;
    }

    __shared__ float aL[SPAN_];          // 9216 B
    __shared__ u16 tl[PXB4][68];         // 17408 B
    __shared__ float red[3][PXB4][10];   // 15360 B
    for (int j = t; j < SPAN_; j += 512) aL[j] = ah[j];

    const int px_l = t & 127;
    const int grp  = t >> 7;             // 0..3
    const int px   = blockIdx.x * PXB4 + px_l;
    const int img  = px / HW_;
    const size_t xbase = (size_t)img * C_ * HW_ + (px - img * HW_);

    float pg[9];
#pragma unroll
    for (int kk = 0; kk < 9; ++kk) pg[kk] = 0.f;
    float ps = 0.f;
    __syncthreads();

#pragma unroll
    for (int ph = 0; ph < 4; ++ph) {     // 64-channel slab per phase
        const int cbase = ph * 64 + grp * 16;
        float R[16];
#pragma unroll
        for (int i = 0; i < 16; ++i)
            R[i] = x[xbase + (size_t)(cbase + i) * HW_];
#pragma unroll
        for (int i = 0; i < 16; ++i) {
            float v = R[i];
            const float* ac = &aL[(cbase + i) * 9];
#pragma unroll
            for (int kk = 0; kk < 9; ++kk) pg[kk] += ac[kk] * v;
            ps += v * v;
            tl[px_l][grp * 16 + i] = f2bf(v);
        }
        __syncthreads();
        // xp write: 1024 16-B chunks (128 px x 128 B), 2 rounds of 512
#pragma unroll
        for (int r = 0; r < 2; ++r) {
            int idx = r * 512 + t;
            int pxl = idx >> 3, ch = idx & 7;
            u16x4 a = *(const u16x4*)&tl[pxl][ch * 8];
            u16x4 b = *(const u16x4*)&tl[pxl][ch * 8 + 4];
            u16x8 v8 = {a[0], a[1], a[2], a[3], b[0], b[1], b[2], b[3]};
            *(u16x8*)&xp[((size_t)(blockIdx.x * PXB4 + pxl)) * C_ +
                         ph * 64 + ch * 8] = v8;
        }
        __syncthreads();
    }

    if (grp > 0) {
#pragma unroll
        for (int kk = 0; kk < 9; ++kk) red[grp - 1][px_l][kk] = pg[kk];
        red[grp - 1][px_l][9] = ps;
    }
    __syncthreads();
    if (grp == 0) {
#pragma unroll
        for (int kk = 0; kk < 9; ++kk) {
            float s = pg[kk] + red[0][px_l][kk] + red[1][px_l][kk] +
                      red[2][px_l][kk];
            g[(size_t)kk * NPIX + px] = s;
        }
        s2[px] = ps + red[0][px_l][9] + red[1][px_l][9] + red[2][px_l][9];
    }
}

// ---- Kernel B2: per-column vote -> histogram --------------------------------
__global__ __launch_bounds__(256) void vote_kernel(const float* __restrict__ g,
                                                   const float* __restrict__ s2,
                                                   const float* __restrict__ ah,
                                                   const float* __restrict__ bh,
                                                   int* __restrict__ counts) {
    __shared__ int hist[8];
    if (threadIdx.x < 8) hist[threadIdx.x] = 0;
    __syncthreads();
    int q = blockIdx.x * 256 + threadIdx.x;
    int n = q / HW_;
    int p = q - n * HW_;
    int h = p / W_;
    int w = p - h * W_;
    float dot = 0.f, ss = 0.f;
#pragma unroll
    for (int kk = 0; kk < 9; ++kk) {
        int dh = kk / 3 - 1, dw = kk % 3 - 1;
        int hh = h + dh, ww = w + dw;
        if (hh >= 0 && hh < H_ && ww >= 0 && ww < W_) {
            int idx = n * HW_ + hh * W_ + ww;
            dot += g[(size_t)kk * NPIX + idx];
            ss  += s2[idx];
        }
    }
    float qext = 0.5f * (ah[SPAN_] + ah[SPAN_ + 1] + ah[SPAN_ + 2]);
    float v = dot / sqrtf(ss) + qext;
    int b = bucketf(v, bh[0]);
    atomicAdd(&hist[b], 1);
    __syncthreads();
    if (threadIdx.x < 8) atomicAdd(&counts[threadIdx.x], hist[threadIdx.x]);
}

// ---- Kernel P2: self-selecting weight fragmentation -------------------------
__global__ __launch_bounds__(256) void prep_w(const float* __restrict__ kern,
                                              const int* __restrict__ kbuck,
                                              const int* __restrict__ counts,
                                              const int* __restrict__ mode,
                                              float* __restrict__ out,
                                              u16* __restrict__ wfrag,
                                              int nfB, int oc_total) {
    __shared__ int sc[256];
    __shared__ int rowsL[512];
    int t = threadIdx.x;
    int best = 0, bc = counts[0];
#pragma unroll
    for (int i = 1; i < 8; ++i) {
        int c = counts[i];
        if (c > bc) { bc = c; best = i; }   // first max wins
    }
    int f0 = (kbuck[t] == best) ? 1 : 0;
    int f1 = (kbuck[t + 256] == best) ? 1 : 0;
    sc[t] = f0 | (f1 << 16);
    __syncthreads();
    for (int off = 1; off < 256; off <<= 1) {
        int add = (t >= off) ? sc[t - off] : 0;
        __syncthreads();
        sc[t] += add;
        __syncthreads();
    }
    int tot = sc[255];
    int t0  = tot & 0xffff;
    int cnt = t0 + (tot >> 16);
    int pos0 = (sc[t] & 0xffff) - f0;
    int pos1 = t0 + (sc[t] >> 16) - f1;
    rowsL[t] = 0; rowsL[t + 256] = 0;
    __syncthreads();
    if (cnt == 0) { rowsL[t] = t; rowsL[t + 256] = t + 256; }
    else {
        if (f0) rowsL[pos0] = t;
        if (f1) rowsL[pos1] = t + 256;
    }
    __syncthreads();
    int ocEff = (cnt == 0) ? OUTC : cnt;
    float scale = (mode[0] && cnt > 0) ? 512.0f / (float)cnt : 1.0f;

    if (blockIdx.x == 0) {                       // rows output (read as f32)
        float* rout = out + (size_t)N_ * oc_total * HW_;
        int nw = ocEff < oc_total ? ocEff : oc_total;
        if (cnt == 0) {
            if (t < nw) rout[t] = (float)t;
            if (t + 256 < nw) rout[t + 256] = (float)(t + 256);
        } else {
            if (f0 && pos0 < nw) rout[pos0] = (float)t;
            if (f1 && pos1 < nw) rout[pos1] = (float)(t + 256);
        }
    }

    // fragmentation: wfrag elem offset ((s*nfB + g)*64 + lane)*8, K = kk*256+c
    int e = blockIdx.x * 256 + t;
    int lane = e & 63;
    int t2 = e >> 6;
    int g = t2 % nfB;
    int s = t2 / nfB;                    // 0..71
    int kk = s >> 3;
    int cb = s & 7;
    int q = lane >> 4;
    int mcol = lane & 15;
    int oc_i = g * 16 + mcol;
    bool valid = oc_i < ocEff;
    int row = valid ? rowsL[oc_i] : 0;
    const float* kr = kern + (size_t)row * SPAN_;
    u16 w8[8];
#pragma unroll
    for (int j = 0; j < 8; ++j) {
        int c = cb * 32 + q * 8 + j;
        float v = valid ? kr[c * 9 + kk] * scale : 0.f;
        w8[j] = f2bf(v);
    }
    u16* dst = wfrag + ((size_t)((s * nfB + g) * 64 + lane)) * 8;
#pragma unroll
    for (int j = 0; j < 8; ++j) dst[j] = w8[j];
}

// ---- Kernel D: MFMA implicit-GEMM conv --------------------------------------
// 4 waves/block, block tile 256 px x 48 oc. A staged via global_load_lds into a
// double-buffered quarter-XOR-swizzled LDS halo; invalid taps read a dedicated
// zeroed slot via 36 precomputed addresses (zero inner-loop VALU); B register-
// pipelined TWO kk ahead (static 3-slot ring), continuous across the cb seam.
__global__ __launch_bounds__(256, 2) void conv_mfma(const u16* __restrict__ xp,
                                                    const u16* __restrict__ wfrag,
                                                    float* __restrict__ out,
                                                    int nfB, int oc_total, int nby) {
    __shared__ char halo[2 * HBYTES];              // 49152 B

    // XCD swizzle: oc-sibling blocks co-located on one XCD; 196 bx = 24*8 + 4.
    int flat = blockIdx.x;
    int bx, by;
    int full = 192 * nby;
    if (flat < full) {
        int gsz = 8 * nby;
        int gi = flat / gsz;
        int tr = flat - gi * gsz;
        by = tr >> 3;
        bx = gi * 8 + (tr & 7);
    } else {
        int tr = flat - full;
        by = tr >> 2;
        bx = 192 + (tr & 3);
    }

    const int t = threadIdx.x;
    const int lane = t & 63;
    const int wv = t >> 6;                         // 0..3
    const int pb = bx * BLKPX;
    const int fb = by * 3;
    const int lane15 = lane & 15;
    const int laneq  = lane >> 4;

    // zero slot 383 of both buffers (never staged; read target for invalid taps)
    if (t < 8) {
        int off = ((t & 4) ? HBYTES : 0) + ZSLOT + (t & 3) * 16;
        *(u16x8*)&halo[off] = (u16x8){0, 0, 0, 0, 0, 0, 0, 0};
    }

    // 36 precomputed ds_read addresses: validity folded (invalid -> zero slot,
    // pre-subtracting the per-kk immediate so addr+IMM lands on slot 383).
    int addrA[4][9];
#pragma unroll
    for (int f = 0; f < 4; ++f) {
        int p = pb + wv * 64 + f * 16 + lane15;
        int img = p / HW_;
        int rp = p - img * HW_;
        int h = rp / W_;
        int w = rp - h * W_;
#pragma unroll
        for (int kk = 0; kk < 9; ++kk) {
            int dh = kk / 3 - 1, dw = kk % 3 - 1;
            int hh = h + dh, ww = w + dw;
            bool val = (hh >= 0) & (hh < H_) & (ww >= 0) & (ww < W_);
            int sn = 57 + wv * 64 + f * 16 + lane15 + dw;
            int base = sn * 64 + ((laneq ^ ((sn >> 1) & 3)) << 4) - 3584;
            addrA[f][kk] = val ? base : (ZSLOT - (kk / 3) * 3584);
        }
    }

    f32x4 acc[4][3];
#pragma unroll
    for (int f = 0; f < 4; ++f)
#pragma unroll
        for (int gg = 0; gg < 3; ++gg) acc[f][gg] = (f32x4){0.f, 0.f, 0.f, 0.f};

    // staging: 6 global_load_lds_dwordx4/thread; LDS dest linear t*16;
    // global source quarter pre-swizzled: q' = (t&3) ^ ((t>>3)&3).
    // r=5, t>=252 skipped so slot 383 stays zero.
    const char* xpb = (const char*)xp;
    const int q4 = (((t & 3) ^ ((t >> 3) & 3)) << 4);
    int gpx[6];
#pragma unroll
    for (int r = 0; r < 6; ++r) {
        int p = pb - 57 + r * 64 + (t >> 2);
        gpx[r] = p < 0 ? 0 : (p >= NPIX ? NPIX - 1 : p);
    }

#pragma unroll
    for (int r = 0; r < 6; ++r) {
        if (r < 5 || t < 252)
            __builtin_amdgcn_global_load_lds(
                (const __attribute__((address_space(1))) unsigned int*)
                    (xpb + (size_t)gpx[r] * 512 + q4),
                (__attribute__((address_space(3))) unsigned int*)
                    &halo[r * 4096 + t * 16],
                16, 0, 0);
    }

    const size_t cbStride = (size_t)nfB * 512;
    const size_t kkStride = cbStride * 8;
    const u16* wl = wfrag + (size_t)fb * 512 + (size_t)lane * 8;
    bf16x8 bB[3][3];                               // 3-slot ring, distance 2
#define LOADB(slot, cb_, kk_) do {                                              \
    const u16* _wp = wl + (size_t)(kk_) * kkStride + (size_t)(cb_) * cbStride;  \
    _Pragma("unroll")                                                           \
    for (int _g = 0; _g < 3; ++_g)                                              \
        bB[slot][_g] = *(const bf16x8*)(_wp + (size_t)_g * 512);                \
} while (0)

    LOADB(0, 0, 0);
    LOADB(1, 0, 1);

#pragma unroll
    for (int cb = 0; cb < 8; ++cb) {
        __syncthreads();                           // buf[cb&1] ready

        if (cb < 7) {                              // stage next cb, other buf
            const int nb = ((cb + 1) & 1) * HBYTES;
#pragma unroll
            for (int r = 0; r < 6; ++r) {
                if (r < 5 || t < 252)
                    __builtin_amdgcn_global_load_lds(
                        (const __attribute__((address_space(1))) unsigned int*)
                            (xpb + (size_t)gpx[r] * 512 + (cb + 1) * 64 + q4),
                        (__attribute__((address_space(3))) unsigned int*)
                            &halo[nb + r * 4096 + t * 16],
                        16, 0, 0);
            }
        }

#pragma unroll
        for (int kk = 0; kk < 9; ++kk) {
            // B prefetch distance 2, continuous across the cb seam
            if (kk < 7)       LOADB((kk + 2) % 3, cb, kk + 2);
            else if (cb < 7)  LOADB((kk + 2) % 3, cb + 1, kk - 7);

            const int IMM = (cb & 1) * HBYTES + (kk / 3) * 3584;  // compile-time
            bf16x8 aX[4];
#pragma unroll
            for (int f = 0; f < 4; ++f)
                aX[f] = *(const bf16x8*)&halo[addrA[f][kk] + IMM];
#pragma unroll
            for (int gg = 0; gg < 3; ++gg)
#pragma unroll
                for (int f = 0; f < 4; ++f)
                    acc[f][gg] = __builtin_amdgcn_mfma_f32_16x16x32_bf16(
                        aX[f], bB[kk % 3][gg], acc[f][gg], 0, 0, 0);
        }
    }
#undef LOADB

    // epilogue: D row (pixel) = (lane>>4)*4 + r, col (oc) = lane&15
#pragma unroll
    for (int f = 0; f < 4; ++f) {
        int p0 = pb + wv * 64 + f * 16 + laneq * 4;
        int img0 = p0 / HW_;
        int hw0 = p0 - img0 * HW_;
#pragma unroll
        for (int gg = 0; gg < 3; ++gg) {
            int oc = (fb + gg) * 16 + lane15;
            if (oc < oc_total) {
                float* op = out + ((size_t)img0 * oc_total + oc) * HW_ + hw0;
                *(f32x4*)op = acc[f][gg];
            }
        }
    }
}

extern "C" void kernel_launch(void* const* d_in, const int* in_sizes, int n_in,
                              void* d_out, int out_size, void* d_ws, size_t ws_size,
                              hipStream_t stream) {
    const float* x    = (const float*)d_in[0];
    const float* kern = (const float*)d_in[1];
    const float* ah   = (const float*)d_in[2];
    const float* bh   = (const float*)d_in[3];
    const int*   mode = (const int*)d_in[4];
    float* out = (float*)d_out;

    // oc is data-dependent but recoverable from out_size: oc*(16*3136+1)
    int oc_total = (out_size % (N_ * HW_ + 1) == 0) ? out_size / (N_ * HW_ + 1)
                                                    : OUTC;
    int nfTot = (oc_total + 15) / 16;
    int nby   = (nfTot + 2) / 3;             // 3 fragments (48 oc) per block
    int nfB   = nby * 3;

    // workspace layout (sized for worst case nfB = 36)
    u16*   xp     = (u16*)d_ws;                                  // NPIX*256
    u16*   wfrag  = xp + (size_t)NPIX * C_;                      // 72*36*64*8
    float* g      = (float*)(wfrag + (size_t)72 * 36 * 64 * 8);  // 9*NPIX
    float* s2     = g + (size_t)9 * NPIX;                        // NPIX
    int*   counts = (int*)(s2 + NPIX);                           // 8
    int*   kbuck  = counts + 8;                                  // 512

    prep4<<<NPB4 + 4, 512, 0, stream>>>(x, ah, bh, kern, xp, g, s2, kbuck,
                                        counts);
    vote_kernel<<<NPIX / 256, 256, 0, stream>>>(g, s2, ah, bh, counts);
    prep_w<<<18 * nfB, 256, 0, stream>>>(kern, kbuck, counts, mode, out, wfrag,
                                         nfB, oc_total);
    conv_mfma<<<(NPIX / BLKPX) * nby, 256, 0, stream>>>(xp, wfrag, out, nfB,
                                                        oc_total, nby);
}

// Round 13
// 113.690 us; speedup vs baseline: 1.3628x; 1.3155x over previous
//
#include <hip/hip_runtime.h>
#include <math.h>

#define N_    16
#define C_    256
#define H_    56
#define W_    56
#define HW_   3136          // H_*W_
#define NPIX  50176         // N_*HW_
#define OUTC  512
#define SPAN_ 2304          // C_*9
#define BLKPX 256           // conv block pixel tile
#define HBYTES 24576        // one halo buffer: 384 slots * 64 B
#define ZSLOT 24512         // byte offset of zero slot (slot 383) in a buffer
#define PXB   128           // prep2 pixel tile
#define NPB   (NPIX / PXB)  // 392 prep2 pixel blocks
#define NVB   (NPIX / 256)  // 196 vote pixel blocks

typedef unsigned short u16;
typedef unsigned int   u32;
typedef __attribute__((ext_vector_type(8))) short bf16x8;
typedef __attribute__((ext_vector_type(8))) unsigned short u16x8;
typedef __attribute__((ext_vector_type(4))) unsigned short u16x4;
typedef __attribute__((ext_vector_type(4))) float f32x4;

__device__ __forceinline__ u16 f2bf(float v) {
    u32 x = __float_as_uint(v);
    u32 r = (x + 0x7fffu + ((x >> 16) & 1u)) >> 16;   // RNE
    return (u16)r;
}

__device__ __forceinline__ int bucketf(float v, float b) {
    int idx = (int)floorf((v + b) / 2.5f);
    int r = idx % 8;
    return r < 0 ? -r : r;
}

// ---- Kernel 1: prep2 -- NCHW f32 -> NHWC bf16 + tap maps (round-10 version) -
// 128 threads, one px per thread; 256 channels in-thread, 16-deep double-
// buffered load batches; per-phase LDS transpose for coalesced xp stores.
__global__ __launch_bounds__(128) void prep2(const float* __restrict__ x,
                                             const float* __restrict__ ah,
                                             u16* __restrict__ xp,
                                             float* __restrict__ g,
                                             float* __restrict__ s2) {
    int t = threadIdx.x;
    __shared__ float aL[SPAN_];          // 9216 B
    __shared__ u16 tl[PXB][68];          // 17408 B
    for (int j = t; j < SPAN_; j += 128) aL[j] = ah[j];

    const int px = blockIdx.x * PXB + t;
    const int img = px / HW_;
    const size_t xbase = (size_t)img * C_ * HW_ + (px - img * HW_);

    float pg[9];
#pragma unroll
    for (int kk = 0; kk < 9; ++kk) pg[kk] = 0.f;
    float ps = 0.f;
    __syncthreads();

    for (int ph = 0; ph < 4; ++ph) {
        float R[16], Rn[16];
#pragma unroll
        for (int i = 0; i < 16; ++i)
            R[i] = x[xbase + (size_t)(ph * 64 + i) * HW_];
#pragma unroll
        for (int sub = 0; sub < 4; ++sub) {
            if (sub < 3) {
#pragma unroll
                for (int i = 0; i < 16; ++i)
                    Rn[i] = x[xbase + (size_t)(ph * 64 + (sub + 1) * 16 + i) * HW_];
            }
#pragma unroll
            for (int i = 0; i < 16; ++i) {
                int c = ph * 64 + sub * 16 + i;
                float v = R[i];
                const float* ac = &aL[c * 9];
#pragma unroll
                for (int kk = 0; kk < 9; ++kk) pg[kk] += ac[kk] * v;
                ps += v * v;
                tl[t][sub * 16 + i] = f2bf(v);
            }
            if (sub < 3) {
#pragma unroll
                for (int i = 0; i < 16; ++i) R[i] = Rn[i];
            }
        }
        __syncthreads();
        // xp write: 16 px-rows x 8 octs per pass, 8 passes
        const int oct = t & 7;
#pragma unroll
        for (int pass = 0; pass < 8; ++pass) {
            int pxl = pass * 16 + (t >> 3);
            u16x8 v8 = *(const u16x8*)&tl[pxl][oct * 8];
            *(u16x8*)&xp[((size_t)(blockIdx.x * PXB + pxl)) * C_ +
                         ph * 64 + oct * 8] = v8;
        }
        __syncthreads();
    }

#pragma unroll
    for (int kk = 0; kk < 9; ++kk) g[(size_t)kk * NPIX + px] = pg[kk];
    s2[px] = ps;
}

// ---- Kernel B2 (+A): vote -> histogram; 128 tail blocks do kbucket ----------
// grid = NVB + 128. Tail: 4 waves/block, ONE WAVE PER OC ROW (9 coalesced
// float4 loads/lane + butterfly reduce) -- spreads the 4.7 MB kern stream
// across ~128 CUs instead of serializing it in a few straggler blocks.
__global__ __launch_bounds__(256) void vote_kernel(const float* __restrict__ g,
                                                   const float* __restrict__ s2,
                                                   const float* __restrict__ ah,
                                                   const float* __restrict__ bh,
                                                   const float* __restrict__ kern,
                                                   int* __restrict__ counts,
                                                   int* __restrict__ kbuck) {
    int kb = blockIdx.x - NVB;
    if (kb >= 0) {
        int wv = threadIdx.x >> 6, lane = threadIdx.x & 63;
        int oc = kb * 4 + wv;
        const float* kr = kern + (size_t)oc * SPAN_;
        float dot = 0.f, ss = 0.f;
#pragma unroll
        for (int i = 0; i < 9; ++i) {
            float4 kv = *(const float4*)(kr + i * 256 + lane * 4);
            float4 av = *(const float4*)(ah + i * 256 + lane * 4);
            dot += kv.x * av.x + kv.y * av.y + kv.z * av.z + kv.w * av.w;
            ss  += kv.x * kv.x + kv.y * kv.y + kv.z * kv.z + kv.w * kv.w;
        }
#pragma unroll
        for (int off = 32; off; off >>= 1) {
            dot += __shfl_xor(dot, off);
            ss  += __shfl_xor(ss, off);
        }
        if (lane == 0) {
            float n2 = ss;            // ||k||^2
            float n4 = n2 * n2;
            float n8 = n4 * n4;
            float v = dot + n2 * ah[SPAN_] + n4 * ah[SPAN_ + 1] +
                      n8 * ah[SPAN_ + 2];
            kbuck[oc] = bucketf(v, bh[0]);
        }
        return;
    }

    __shared__ int hist[8];
    if (threadIdx.x < 8) hist[threadIdx.x] = 0;
    __syncthreads();
    int q = blockIdx.x * 256 + threadIdx.x;
    int n = q / HW_;
    int p = q - n * HW_;
    int h = p / W_;
    int w = p - h * W_;
    float dot = 0.f, ss = 0.f;
#pragma unroll
    for (int kk = 0; kk < 9; ++kk) {
        int dh = kk / 3 - 1, dw = kk % 3 - 1;
        int hh = h + dh, ww = w + dw;
        if (hh >= 0 && hh < H_ && ww >= 0 && ww < W_) {
            int idx = n * HW_ + hh * W_ + ww;
            dot += g[(size_t)kk * NPIX + idx];
            ss  += s2[idx];
        }
    }
    float qext = 0.5f * (ah[SPAN_] + ah[SPAN_ + 1] + ah[SPAN_ + 2]);
    float v = dot / sqrtf(ss) + qext;
    int b = bucketf(v, bh[0]);
    atomicAdd(&hist[b], 1);
    __syncthreads();
    if (threadIdx.x < 8) atomicAdd(&counts[threadIdx.x], hist[threadIdx.x]);
}

// ---- Kernel P2: self-selecting weight fragmentation -------------------------
__global__ __launch_bounds__(256) void prep_w(const float* __restrict__ kern,
                                              const int* __restrict__ kbuck,
                                              const int* __restrict__ counts,
                                              const int* __restrict__ mode,
                                              float* __restrict__ out,
                                              u16* __restrict__ wfrag,
                                              int nfB, int oc_total) {
    __shared__ int sc[256];
    __shared__ int rowsL[512];
    int t = threadIdx.x;
    int best = 0, bc = counts[0];
#pragma unroll
    for (int i = 1; i < 8; ++i) {
        int c = counts[i];
        if (c > bc) { bc = c; best = i; }   // first max wins
    }
    int f0 = (kbuck[t] == best) ? 1 : 0;
    int f1 = (kbuck[t + 256] == best) ? 1 : 0;
    sc[t] = f0 | (f1 << 16);
    __syncthreads();
    for (int off = 1; off < 256; off <<= 1) {
        int add = (t >= off) ? sc[t - off] : 0;
        __syncthreads();
        sc[t] += add;
        __syncthreads();
    }
    int tot = sc[255];
    int t0  = tot & 0xffff;
    int cnt = t0 + (tot >> 16);
    int pos0 = (sc[t] & 0xffff) - f0;
    int pos1 = t0 + (sc[t] >> 16) - f1;
    rowsL[t] = 0; rowsL[t + 256] = 0;
    __syncthreads();
    if (cnt == 0) { rowsL[t] = t; rowsL[t + 256] = t + 256; }
    else {
        if (f0) rowsL[pos0] = t;
        if (f1) rowsL[pos1] = t + 256;
    }
    __syncthreads();
    int ocEff = (cnt == 0) ? OUTC : cnt;
    float scale = (mode[0] && cnt > 0) ? 512.0f / (float)cnt : 1.0f;

    if (blockIdx.x == 0) {                       // rows output (read as f32)
        float* rout = out + (size_t)N_ * oc_total * HW_;
        int nw = ocEff < oc_total ? ocEff : oc_total;
        if (cnt == 0) {
            if (t < nw) rout[t] = (float)t;
            if (t + 256 < nw) rout[t + 256] = (float)(t + 256);
        } else {
            if (f0 && pos0 < nw) rout[pos0] = (float)t;
            if (f1 && pos1 < nw) rout[pos1] = (float)(t + 256);
        }
    }

    // fragmentation: wfrag elem offset ((s*nfB + g)*64 + lane)*8, K = kk*256+c
    int e = blockIdx.x * 256 + t;
    int lane = e & 63;
    int t2 = e >> 6;
    int g = t2 % nfB;
    int s = t2 / nfB;                    // 0..71
    int kk = s >> 3;
    int cb = s & 7;
    int q = lane >> 4;
    int mcol = lane & 15;
    int oc_i = g * 16 + mcol;
    bool valid = oc_i < ocEff;
    int row = valid ? rowsL[oc_i] : 0;
    const float* kr = kern + (size_t)row * SPAN_;
    u16 w8[8];
#pragma unroll
    for (int j = 0; j < 8; ++j) {
        int c = cb * 32 + q * 8 + j;
        float v = valid ? kr[c * 9 + kk] * scale : 0.f;
        w8[j] = f2bf(v);
    }
    u16* dst = wfrag + ((size_t)((s * nfB + g) * 64 + lane)) * 8;
#pragma unroll
    for (int j = 0; j < 8; ++j) dst[j] = w8[j];
}

// ---- Kernel D: MFMA implicit-GEMM conv (round-12 version, unchanged) --------
// 4 waves/block, block tile 256 px x 48 oc. A staged via global_load_lds into a
// double-buffered quarter-XOR-swizzled LDS halo; invalid taps read a dedicated
// zeroed slot via 36 precomputed addresses (zero inner-loop VALU); B register-
// pipelined TWO kk ahead (static 3-slot ring), continuous across the cb seam.
__global__ __launch_bounds__(256, 2) void conv_mfma(const u16* __restrict__ xp,
                                                    const u16* __restrict__ wfrag,
                                                    float* __restrict__ out,
                                                    int nfB, int oc_total, int nby) {
    __shared__ char halo[2 * HBYTES];              // 49152 B

    // XCD swizzle: oc-sibling blocks co-located on one XCD; 196 bx = 24*8 + 4.
    int flat = blockIdx.x;
    int bx, by;
    int full = 192 * nby;
    if (flat < full) {
        int gsz = 8 * nby;
        int gi = flat / gsz;
        int tr = flat - gi * gsz;
        by = tr >> 3;
        bx = gi * 8 + (tr & 7);
    } else {
        int tr = flat - full;
        by = tr >> 2;
        bx = 192 + (tr & 3);
    }

    const int t = threadIdx.x;
    const int lane = t & 63;
    const int wv = t >> 6;                         // 0..3
    const int pb = bx * BLKPX;
    const int fb = by * 3;
    const int lane15 = lane & 15;
    const int laneq  = lane >> 4;

    // zero slot 383 of both buffers (never staged; read target for invalid taps)
    if (t < 8) {
        int off = ((t & 4) ? HBYTES : 0) + ZSLOT + (t & 3) * 16;
        *(u16x8*)&halo[off] = (u16x8){0, 0, 0, 0, 0, 0, 0, 0};
    }

    // 36 precomputed ds_read addresses: validity folded (invalid -> zero slot,
    // pre-subtracting the per-kk immediate so addr+IMM lands on slot 383).
    int addrA[4][9];
#pragma unroll
    for (int f = 0; f < 4; ++f) {
        int p = pb + wv * 64 + f * 16 + lane15;
        int img = p / HW_;
        int rp = p - img * HW_;
        int h = rp / W_;
        int w = rp - h * W_;
#pragma unroll
        for (int kk = 0; kk < 9; ++kk) {
            int dh = kk / 3 - 1, dw = kk % 3 - 1;
            int hh = h + dh, ww = w + dw;
            bool val = (hh >= 0) & (hh < H_) & (ww >= 0) & (ww < W_);
            int sn = 57 + wv * 64 + f * 16 + lane15 + dw;
            int base = sn * 64 + ((laneq ^ ((sn >> 1) & 3)) << 4) - 3584;
            addrA[f][kk] = val ? base : (ZSLOT - (kk / 3) * 3584);
        }
    }

    f32x4 acc[4][3];
#pragma unroll
    for (int f = 0; f < 4; ++f)
#pragma unroll
        for (int gg = 0; gg < 3; ++gg) acc[f][gg] = (f32x4){0.f, 0.f, 0.f, 0.f};

    // staging: 6 global_load_lds_dwordx4/thread; LDS dest linear t*16;
    // global source quarter pre-swizzled: q' = (t&3) ^ ((t>>3)&3).
    // r=5, t>=252 skipped so slot 383 stays zero.
    const char* xpb = (const char*)xp;
    const int q4 = (((t & 3) ^ ((t >> 3) & 3)) << 4);
    int gpx[6];
#pragma unroll
    for (int r = 0; r < 6; ++r) {
        int p = pb - 57 + r * 64 + (t >> 2);
        gpx[r] = p < 0 ? 0 : (p >= NPIX ? NPIX - 1 : p);
    }

#pragma unroll
    for (int r = 0; r < 6; ++r) {
        if (r < 5 || t < 252)
            __builtin_amdgcn_global_load_lds(
                (const __attribute__((address_space(1))) unsigned int*)
                    (xpb + (size_t)gpx[r] * 512 + q4),
                (__attribute__((address_space(3))) unsigned int*)
                    &halo[r * 4096 + t * 16],
                16, 0, 0);
    }

    const size_t cbStride = (size_t)nfB * 512;
    const size_t kkStride = cbStride * 8;
    const u16* wl = wfrag + (size_t)fb * 512 + (size_t)lane * 8;
    bf16x8 bB[3][3];                               // 3-slot ring, distance 2
#define LOADB(slot, cb_, kk_) do {                                              \
    const u16* _wp = wl + (size_t)(kk_) * kkStride + (size_t)(cb_) * cbStride;  \
    _Pragma("unroll")                                                           \
    for (int _g = 0; _g < 3; ++_g)                                              \
        bB[slot][_g] = *(const bf16x8*)(_wp + (size_t)_g * 512);                \
} while (0)

    LOADB(0, 0, 0);
    LOADB(1, 0, 1);

#pragma unroll
    for (int cb = 0; cb < 8; ++cb) {
        __syncthreads();                           // buf[cb&1] ready

        if (cb < 7) {                              // stage next cb, other buf
            const int nb = ((cb + 1) & 1) * HBYTES;
#pragma unroll
            for (int r = 0; r < 6; ++r) {
                if (r < 5 || t < 252)
                    __builtin_amdgcn_global_load_lds(
                        (const __attribute__((address_space(1))) unsigned int*)
                            (xpb + (size_t)gpx[r] * 512 + (cb + 1) * 64 + q4),
                        (__attribute__((address_space(3))) unsigned int*)
                            &halo[nb + r * 4096 + t * 16],
                        16, 0, 0);
            }
        }

#pragma unroll
        for (int kk = 0; kk < 9; ++kk) {
            // B prefetch distance 2, continuous across the cb seam
            if (kk < 7)       LOADB((kk + 2) % 3, cb, kk + 2);
            else if (cb < 7)  LOADB((kk + 2) % 3, cb + 1, kk - 7);

            const int IMM = (cb & 1) * HBYTES + (kk / 3) * 3584;  // compile-time
            bf16x8 aX[4];
#pragma unroll
            for (int f = 0; f < 4; ++f)
                aX[f] = *(const bf16x8*)&halo[addrA[f][kk] + IMM];
#pragma unroll
            for (int gg = 0; gg < 3; ++gg)
#pragma unroll
                for (int f = 0; f < 4; ++f)
                    acc[f][gg] = __builtin_amdgcn_mfma_f32_16x16x32_bf16(
                        aX[f], bB[kk % 3][gg], acc[f][gg], 0, 0, 0);
        }
    }
#undef LOADB

    // epilogue: D row (pixel) = (lane>>4)*4 + r, col (oc) = lane&15
#pragma unroll
    for (int f = 0; f < 4; ++f) {
        int p0 = pb + wv * 64 + f * 16 + laneq * 4;
        int img0 = p0 / HW_;
        int hw0 = p0 - img0 * HW_;
#pragma unroll
        for (int gg = 0; gg < 3; ++gg) {
            int oc = (fb + gg) * 16 + lane15;
            if (oc < oc_total) {
                float* op = out + ((size_t)img0 * oc_total + oc) * HW_ + hw0;
                *(f32x4*)op = acc[f][gg];
            }
        }
    }
}

extern "C" void kernel_launch(void* const* d_in, const int* in_sizes, int n_in,
                              void* d_out, int out_size, void* d_ws, size_t ws_size,
                              hipStream_t stream) {
    const float* x    = (const float*)d_in[0];
    const float* kern = (const float*)d_in[1];
    const float* ah   = (const float*)d_in[2];
    const float* bh   = (const float*)d_in[3];
    const int*   mode = (const int*)d_in[4];
    float* out = (float*)d_out;

    // oc is data-dependent but recoverable from out_size: oc*(16*3136+1)
    int oc_total = (out_size % (N_ * HW_ + 1) == 0) ? out_size / (N_ * HW_ + 1)
                                                    : OUTC;
    int nfTot = (oc_total + 15) / 16;
    int nby   = (nfTot + 2) / 3;             // 3 fragments (48 oc) per block
    int nfB   = nby * 3;

    // workspace layout (sized for worst case nfB = 36)
    u16*   xp     = (u16*)d_ws;                                  // NPIX*256
    u16*   wfrag  = xp + (size_t)NPIX * C_;                      // 72*36*64*8
    float* g      = (float*)(wfrag + (size_t)72 * 36 * 64 * 8);  // 9*NPIX
    float* s2     = g + (size_t)9 * NPIX;                        // NPIX
    int*   counts = (int*)(s2 + NPIX);                           // 8
    int*   kbuck  = counts + 8;                                  // 512

    hipMemsetAsync(counts, 0, 8 * sizeof(int), stream);

    prep2<<<NPB, 128, 0, stream>>>(x, ah, xp, g, s2);
    vote_kernel<<<NVB + 128, 256, 0, stream>>>(g, s2, ah, bh, kern, counts,
                                               kbuck);
    prep_w<<<18 * nfB, 256, 0, stream>>>(kern, kbuck, counts, mode, out, wfrag,
                                         nfB, oc_total);
    conv_mfma<<<(NPIX / BLKPX) * nby, 256, 0, stream>>>(xp, wfrag, out, nfB,
                                                        oc_total, nby);
}

// Round 14
// 98.723 us; speedup vs baseline: 1.5695x; 1.1516x over previous
//
#include <hip/hip_runtime.h>
#include <math.h>

#define N_    16
#define C_    256
#define H_    56
#define W_    56
#define HW_   3136          // H_*W_
#define NPIX  50176         // N_*HW_
#define OUTC  512
#define SPAN_ 2304          // C_*9
#define BLKPX 128           // conv block pixel tile
#define HSLOTS 256          // halo slots per buffer (need 128+114=242)
#define HBYTES (HSLOTS * 64) // 16384 B per buffer
#define PXB   128           // prep2 pixel tile
#define NPB   (NPIX / PXB)  // 392 prep2 pixel blocks
#define NVB   (NPIX / 256)  // 196 vote pixel blocks

typedef unsigned short u16;
typedef unsigned int   u32;
typedef __attribute__((ext_vector_type(8))) short bf16x8;
typedef __attribute__((ext_vector_type(8))) unsigned short u16x8;
typedef __attribute__((ext_vector_type(4))) unsigned short u16x4;
typedef __attribute__((ext_vector_type(4))) float f32x4;

__device__ __forceinline__ u16 f2bf(float v) {
    u32 x = __float_as_uint(v);
    u32 r = (x + 0x7fffu + ((x >> 16) & 1u)) >> 16;   // RNE
    return (u16)r;
}

__device__ __forceinline__ int bucketf(float v, float b) {
    int idx = (int)floorf((v + b) / 2.5f);
    int r = idx % 8;
    return r < 0 ? -r : r;
}

// ---- Kernel 1: prep2 -- NCHW f32 -> NHWC bf16 + tap maps (round-10 version) -
__global__ __launch_bounds__(128) void prep2(const float* __restrict__ x,
                                             const float* __restrict__ ah,
                                             u16* __restrict__ xp,
                                             float* __restrict__ g,
                                             float* __restrict__ s2) {
    int t = threadIdx.x;
    __shared__ float aL[SPAN_];          // 9216 B
    __shared__ u16 tl[PXB][68];          // 17408 B
    for (int j = t; j < SPAN_; j += 128) aL[j] = ah[j];

    const int px = blockIdx.x * PXB + t;
    const int img = px / HW_;
    const size_t xbase = (size_t)img * C_ * HW_ + (px - img * HW_);

    float pg[9];
#pragma unroll
    for (int kk = 0; kk < 9; ++kk) pg[kk] = 0.f;
    float ps = 0.f;
    __syncthreads();

    for (int ph = 0; ph < 4; ++ph) {
        float R[16], Rn[16];
#pragma unroll
        for (int i = 0; i < 16; ++i)
            R[i] = x[xbase + (size_t)(ph * 64 + i) * HW_];
#pragma unroll
        for (int sub = 0; sub < 4; ++sub) {
            if (sub < 3) {
#pragma unroll
                for (int i = 0; i < 16; ++i)
                    Rn[i] = x[xbase + (size_t)(ph * 64 + (sub + 1) * 16 + i) * HW_];
            }
#pragma unroll
            for (int i = 0; i < 16; ++i) {
                int c = ph * 64 + sub * 16 + i;
                float v = R[i];
                const float* ac = &aL[c * 9];
#pragma unroll
                for (int kk = 0; kk < 9; ++kk) pg[kk] += ac[kk] * v;
                ps += v * v;
                tl[t][sub * 16 + i] = f2bf(v);
            }
            if (sub < 3) {
#pragma unroll
                for (int i = 0; i < 16; ++i) R[i] = Rn[i];
            }
        }
        __syncthreads();
        const int oct = t & 7;
#pragma unroll
        for (int pass = 0; pass < 8; ++pass) {
            int pxl = pass * 16 + (t >> 3);
            u16x8 v8 = *(const u16x8*)&tl[pxl][oct * 8];
            *(u16x8*)&xp[((size_t)(blockIdx.x * PXB + pxl)) * C_ +
                         ph * 64 + oct * 8] = v8;
        }
        __syncthreads();
    }

#pragma unroll
    for (int kk = 0; kk < 9; ++kk) g[(size_t)kk * NPIX + px] = pg[kk];
    s2[px] = ps;
}

// ---- Kernel B2 (+A): vote -> histogram; 128 tail blocks do kbucket ----------
__global__ __launch_bounds__(256) void vote_kernel(const float* __restrict__ g,
                                                   const float* __restrict__ s2,
                                                   const float* __restrict__ ah,
                                                   const float* __restrict__ bh,
                                                   const float* __restrict__ kern,
                                                   int* __restrict__ counts,
                                                   int* __restrict__ kbuck) {
    int kb = blockIdx.x - NVB;
    if (kb >= 0) {
        int wv = threadIdx.x >> 6, lane = threadIdx.x & 63;
        int oc = kb * 4 + wv;
        const float* kr = kern + (size_t)oc * SPAN_;
        float dot = 0.f, ss = 0.f;
#pragma unroll
        for (int i = 0; i < 9; ++i) {
            float4 kv = *(const float4*)(kr + i * 256 + lane * 4);
            float4 av = *(const float4*)(ah + i * 256 + lane * 4);
            dot += kv.x * av.x + kv.y * av.y + kv.z * av.z + kv.w * av.w;
            ss  += kv.x * kv.x + kv.y * kv.y + kv.z * kv.z + kv.w * kv.w;
        }
#pragma unroll
        for (int off = 32; off; off >>= 1) {
            dot += __shfl_xor(dot, off);
            ss  += __shfl_xor(ss, off);
        }
        if (lane == 0) {
            float n2 = ss;            // ||k||^2
            float n4 = n2 * n2;
            float n8 = n4 * n4;
            float v = dot + n2 * ah[SPAN_] + n4 * ah[SPAN_ + 1] +
                      n8 * ah[SPAN_ + 2];
            kbuck[oc] = bucketf(v, bh[0]);
        }
        return;
    }

    __shared__ int hist[8];
    if (threadIdx.x < 8) hist[threadIdx.x] = 0;
    __syncthreads();
    int q = blockIdx.x * 256 + threadIdx.x;
    int n = q / HW_;
    int p = q - n * HW_;
    int h = p / W_;
    int w = p - h * W_;
    float dot = 0.f, ss = 0.f;
#pragma unroll
    for (int kk = 0; kk < 9; ++kk) {
        int dh = kk / 3 - 1, dw = kk % 3 - 1;
        int hh = h + dh, ww = w + dw;
        if (hh >= 0 && hh < H_ && ww >= 0 && ww < W_) {
            int idx = n * HW_ + hh * W_ + ww;
            dot += g[(size_t)kk * NPIX + idx];
            ss  += s2[idx];
        }
    }
    float qext = 0.5f * (ah[SPAN_] + ah[SPAN_ + 1] + ah[SPAN_ + 2]);
    float v = dot / sqrtf(ss) + qext;
    int b = bucketf(v, bh[0]);
    atomicAdd(&hist[b], 1);
    __syncthreads();
    if (threadIdx.x < 8) atomicAdd(&counts[threadIdx.x], hist[threadIdx.x]);
}

// ---- Kernel P2: self-selecting weight fragmentation -------------------------
__global__ __launch_bounds__(256) void prep_w(const float* __restrict__ kern,
                                              const int* __restrict__ kbuck,
                                              const int* __restrict__ counts,
                                              const int* __restrict__ mode,
                                              float* __restrict__ out,
                                              u16* __restrict__ wfrag,
                                              int nfB, int oc_total) {
    __shared__ int sc[256];
    __shared__ int rowsL[512];
    int t = threadIdx.x;
    int best = 0, bc = counts[0];
#pragma unroll
    for (int i = 1; i < 8; ++i) {
        int c = counts[i];
        if (c > bc) { bc = c; best = i; }   // first max wins
    }
    int f0 = (kbuck[t] == best) ? 1 : 0;
    int f1 = (kbuck[t + 256] == best) ? 1 : 0;
    sc[t] = f0 | (f1 << 16);
    __syncthreads();
    for (int off = 1; off < 256; off <<= 1) {
        int add = (t >= off) ? sc[t - off] : 0;
        __syncthreads();
        sc[t] += add;
        __syncthreads();
    }
    int tot = sc[255];
    int t0  = tot & 0xffff;
    int cnt = t0 + (tot >> 16);
    int pos0 = (sc[t] & 0xffff) - f0;
    int pos1 = t0 + (sc[t] >> 16) - f1;
    rowsL[t] = 0; rowsL[t + 256] = 0;
    __syncthreads();
    if (cnt == 0) { rowsL[t] = t; rowsL[t + 256] = t + 256; }
    else {
        if (f0) rowsL[pos0] = t;
        if (f1) rowsL[pos1] = t + 256;
    }
    __syncthreads();
    int ocEff = (cnt == 0) ? OUTC : cnt;
    float scale = (mode[0] && cnt > 0) ? 512.0f / (float)cnt : 1.0f;

    if (blockIdx.x == 0) {                       // rows output (read as f32)
        float* rout = out + (size_t)N_ * oc_total * HW_;
        int nw = ocEff < oc_total ? ocEff : oc_total;
        if (cnt == 0) {
            if (t < nw) rout[t] = (float)t;
            if (t + 256 < nw) rout[t + 256] = (float)(t + 256);
        } else {
            if (f0 && pos0 < nw) rout[pos0] = (float)t;
            if (f1 && pos1 < nw) rout[pos1] = (float)(t + 256);
        }
    }

    // fragmentation: wfrag elem offset ((s*nfB + g)*64 + lane)*8, K = kk*256+c
    int e = blockIdx.x * 256 + t;
    int lane = e & 63;
    int t2 = e >> 6;
    int g = t2 % nfB;
    int s = t2 / nfB;                    // 0..71
    int kk = s >> 3;
    int cb = s & 7;
    int q = lane >> 4;
    int mcol = lane & 15;
    int oc_i = g * 16 + mcol;
    bool valid = oc_i < ocEff;
    int row = valid ? rowsL[oc_i] : 0;
    const float* kr = kern + (size_t)row * SPAN_;
    u16 w8[8];
#pragma unroll
    for (int j = 0; j < 8; ++j) {
        int c = cb * 32 + q * 8 + j;
        float v = valid ? kr[c * 9 + kk] * scale : 0.f;
        w8[j] = f2bf(v);
    }
    u16* dst = wfrag + ((size_t)((s * nfB + g) * 64 + lane)) * 8;
#pragma unroll
    for (int j = 0; j < 8; ++j) dst[j] = w8[j];
}

// ---- Kernel D: MFMA implicit-GEMM conv (round-9 structure, 128-px tiles) ----
// 4 waves/block, block tile 128 px x 48 oc (wave = 32 px, acc[2][3]).
// A staged via global_load_lds into a double-buffered quarter-XOR-swizzled LDS
// halo (32 KB total); invalid taps masked by cndmask (conflict-free, measured);
// B register-pipelined one kk ahead, continuous across the cb seam.
__global__ __launch_bounds__(256, 2) void conv_mfma(const u16* __restrict__ xp,
                                                    const u16* __restrict__ wfrag,
                                                    float* __restrict__ out,
                                                    int nfB, int oc_total, int nby) {
    __shared__ char halo[2 * HBYTES];              // 32768 B

    // bijective XCD swizzle (grid = 392*nby, 1176 % 8 == 0)
    const int tot = (NPIX / BLKPX) * nby;
    const int q8 = tot >> 3;
    const int flat = blockIdx.x;
    const int virt = (flat & 7) * q8 + (flat >> 3);
    const int bx = virt / nby;
    const int by = virt - bx * nby;

    const int t = threadIdx.x;
    const int lane = t & 63;
    const int wv = t >> 6;                         // 0..3
    const int pb = bx * BLKPX;
    const int fb = by * 3;
    const int lane15 = lane & 15;
    const int laneq  = lane >> 4;

    // per-fragment validity masks (bit kk) + swizzled LDS read bases per dw.
    // base holds -3584 bias so the ds_read immediate (dh+1)*3584 stays >= 0.
    u32 valMask[2];
    int aB[2][3];
#pragma unroll
    for (int f = 0; f < 2; ++f) {
        int p = pb + wv * 32 + f * 16 + lane15;
        int img = p / HW_;
        int rp = p - img * HW_;
        int h = rp / W_;
        int w = rp - h * W_;
        u32 m = 0;
#pragma unroll
        for (int kk = 0; kk < 9; ++kk) {
            int dh = kk / 3 - 1, dw = kk % 3 - 1;
            int hh = h + dh, ww = w + dw;
            if (hh >= 0 && hh < H_ && ww >= 0 && ww < W_) m |= (1u << kk);
        }
        valMask[f] = m;
#pragma unroll
        for (int j = 0; j < 3; ++j) {               // dw = j-1
            int sn = 57 + wv * 32 + f * 16 + lane15 + (j - 1);
            aB[f][j] = sn * 64 + ((laneq ^ ((sn >> 1) & 3)) << 4) - 3584;
        }
    }

    f32x4 acc[2][3];
#pragma unroll
    for (int f = 0; f < 2; ++f)
#pragma unroll
        for (int gg = 0; gg < 3; ++gg) acc[f][gg] = (f32x4){0.f, 0.f, 0.f, 0.f};
    const bf16x8 zf = {0, 0, 0, 0, 0, 0, 0, 0};

    // staging: 4 global_load_lds_dwordx4/thread (slots 0..241); LDS dest linear
    // t*16; global source quarter pre-swizzled: q' = (t&3) ^ ((t>>3)&3).
    const char* xpb = (const char*)xp;
    const int q4 = (((t & 3) ^ ((t >> 3) & 3)) << 4);
    int gpx[4];
#pragma unroll
    for (int r = 0; r < 4; ++r) {
        int p = pb - 57 + r * 64 + (t >> 2);
        gpx[r] = p < 0 ? 0 : (p >= NPIX ? NPIX - 1 : p);
    }

#pragma unroll
    for (int r = 0; r < 4; ++r) {
        if (r < 3 || t < 200)                       // slots >= 242 unused
            __builtin_amdgcn_global_load_lds(
                (const __attribute__((address_space(1))) unsigned int*)
                    (xpb + (size_t)gpx[r] * 512 + q4),
                (__attribute__((address_space(3))) unsigned int*)
                    &halo[r * 4096 + t * 16],
                16, 0, 0);
    }

    const size_t cbStride = (size_t)nfB * 512;
    const size_t kkStride = cbStride * 8;
    const u16* wl = wfrag + (size_t)fb * 512 + (size_t)lane * 8;
    bf16x8 bW[3], bWn[3];
#define LOADB(dst, cb_, kk_) do {                                               \
    const u16* _wp = wl + (size_t)(kk_) * kkStride + (size_t)(cb_) * cbStride;  \
    _Pragma("unroll")                                                           \
    for (int _g = 0; _g < 3; ++_g)                                              \
        dst[_g] = *(const bf16x8*)(_wp + (size_t)_g * 512);                     \
} while (0)

    LOADB(bW, 0, 0);

#pragma unroll
    for (int cb = 0; cb < 8; ++cb) {
        __syncthreads();                           // buf[cb&1] ready

        if (cb < 7) {                              // stage next cb, other buf
            const int nb = ((cb + 1) & 1) * HBYTES;
#pragma unroll
            for (int r = 0; r < 4; ++r) {
                if (r < 3 || t < 200)
                    __builtin_amdgcn_global_load_lds(
                        (const __attribute__((address_space(1))) unsigned int*)
                            (xpb + (size_t)gpx[r] * 512 + (cb + 1) * 64 + q4),
                        (__attribute__((address_space(3))) unsigned int*)
                            &halo[nb + r * 4096 + t * 16],
                        16, 0, 0);
            }
        }

#pragma unroll
        for (int kk = 0; kk < 9; ++kk) {
            // B prefetch distance 1, continuous across the cb seam
            if (kk < 8)       LOADB(bWn, cb, kk + 1);
            else if (cb < 7)  LOADB(bWn, cb + 1, 0);

            const int dh = kk / 3 - 1;
            const int j  = kk % 3;                 // dw + 1
            const int IMM = (cb & 1) * HBYTES + (dh + 1) * 3584;  // compile-time
            bf16x8 aX[2];
#pragma unroll
            for (int f = 0; f < 2; ++f) {
                bf16x8 a = *(const bf16x8*)&halo[aB[f][j] + IMM];
                aX[f] = ((valMask[f] >> kk) & 1) ? a : zf;
            }
#pragma unroll
            for (int gg = 0; gg < 3; ++gg)
#pragma unroll
                for (int f = 0; f < 2; ++f)
                    acc[f][gg] = __builtin_amdgcn_mfma_f32_16x16x32_bf16(
                        aX[f], bW[gg], acc[f][gg], 0, 0, 0);
            if (kk < 8 || cb < 7) {
#pragma unroll
                for (int gg = 0; gg < 3; ++gg) bW[gg] = bWn[gg];
            }
        }
    }
#undef LOADB

    // epilogue: D row (pixel) = (lane>>4)*4 + r, col (oc) = lane&15
#pragma unroll
    for (int f = 0; f < 2; ++f) {
        int p0 = pb + wv * 32 + f * 16 + laneq * 4;
        int img0 = p0 / HW_;
        int hw0 = p0 - img0 * HW_;
#pragma unroll
        for (int gg = 0; gg < 3; ++gg) {
            int oc = (fb + gg) * 16 + lane15;
            if (oc < oc_total) {
                float* op = out + ((size_t)img0 * oc_total + oc) * HW_ + hw0;
                *(f32x4*)op = acc[f][gg];
            }
        }
    }
}

extern "C" void kernel_launch(void* const* d_in, const int* in_sizes, int n_in,
                              void* d_out, int out_size, void* d_ws, size_t ws_size,
                              hipStream_t stream) {
    const float* x    = (const float*)d_in[0];
    const float* kern = (const float*)d_in[1];
    const float* ah   = (const float*)d_in[2];
    const float* bh   = (const float*)d_in[3];
    const int*   mode = (const int*)d_in[4];
    float* out = (float*)d_out;

    // oc is data-dependent but recoverable from out_size: oc*(16*3136+1)
    int oc_total = (out_size % (N_ * HW_ + 1) == 0) ? out_size / (N_ * HW_ + 1)
                                                    : OUTC;
    int nfTot = (oc_total + 15) / 16;
    int nby   = (nfTot + 2) / 3;             // 3 fragments (48 oc) per block
    int nfB   = nby * 3;

    // workspace layout (sized for worst case nfB = 36)
    u16*   xp     = (u16*)d_ws;                                  // NPIX*256
    u16*   wfrag  = xp + (size_t)NPIX * C_;                      // 72*36*64*8
    float* g      = (float*)(wfrag + (size_t)72 * 36 * 64 * 8);  // 9*NPIX
    float* s2     = g + (size_t)9 * NPIX;                        // NPIX
    int*   counts = (int*)(s2 + NPIX);                           // 8
    int*   kbuck  = counts + 8;                                  // 512

    hipMemsetAsync(counts, 0, 8 * sizeof(int), stream);

    prep2<<<NPB, 128, 0, stream>>>(x, ah, xp, g, s2);
    vote_kernel<<<NVB + 128, 256, 0, stream>>>(g, s2, ah, bh, kern, counts,
                                               kbuck);
    prep_w<<<18 * nfB, 256, 0, stream>>>(kern, kbuck, counts, mode, out, wfrag,
                                         nfB, oc_total);
    conv_mfma<<<(NPIX / BLKPX) * nby, 256, 0, stream>>>(xp, wfrag, out, nfB,
                                                        oc_total, nby);
}

// Round 15
// 91.120 us; speedup vs baseline: 1.7004x; 1.0834x over previous
//
#include <hip/hip_runtime.h>
#include <math.h>

#define N_    16
#define C_    256
#define H_    56
#define W_    56
#define HW_   3136          // H_*W_
#define NPIX  50176         // N_*HW_
#define OUTC  512
#define SPAN_ 2304          // C_*9
#define BLKPX 256           // conv block pixel tile
#define HBYTES 24576        // one halo buffer: 384 slots * 64 B
#define PXB   128           // prep2 pixel tile
#define NPB2  (2 * NPIX / PXB) // 784 prep2 blocks (2 channel-halves per tile)
#define NVB   (NPIX / 256)  // 196 vote pixel blocks

typedef unsigned short u16;
typedef unsigned int   u32;
typedef __attribute__((ext_vector_type(8))) short bf16x8;
typedef __attribute__((ext_vector_type(8))) unsigned short u16x8;
typedef __attribute__((ext_vector_type(4))) unsigned short u16x4;
typedef __attribute__((ext_vector_type(4))) float f32x4;

__device__ __forceinline__ u16 f2bf(float v) {
    u32 x = __float_as_uint(v);
    u32 r = (x + 0x7fffu + ((x >> 16) & 1u)) >> 16;   // RNE
    return (u16)r;
}

__device__ __forceinline__ int bucketf(float v, float b) {
    int idx = (int)floorf((v + b) / 2.5f);
    int r = idx % 8;
    return r < 0 ? -r : r;
}

// ---- Kernel 1: prep2h -- NCHW f32 -> NHWC bf16 + tap-map PARTIALS -----------
// grid = 784: block b handles px tile (b>>1)*128, channel half (b&1)*128..+127.
// Same verified structure as round-10 prep2 (16-deep double-buffered loads,
// LDS transpose for coalesced xp stores); partial pg/ps written to g0/g1,
// s2a/s2b (deterministic, no atomics). Halves the serial chain, doubles waves.
__global__ __launch_bounds__(128) void prep2h(const float* __restrict__ x,
                                              const float* __restrict__ ah,
                                              u16* __restrict__ xp,
                                              float* __restrict__ gp,
                                              float* __restrict__ s2p) {
    int t = threadIdx.x;
    const int half = blockIdx.x & 1;
    const int tile = blockIdx.x >> 1;
    const int coff = half * 128;          // channel base for this block

    __shared__ float aL[128 * 9];         // 4608 B (this half's taps)
    __shared__ u16 tl[PXB][68];           // 17408 B
    for (int j = t; j < 128 * 9; j += 128) aL[j] = ah[coff * 9 + j];

    const int px = tile * PXB + t;
    const int img = px / HW_;
    const size_t xbase = (size_t)img * C_ * HW_ + (px - img * HW_);

    float pg[9];
#pragma unroll
    for (int kk = 0; kk < 9; ++kk) pg[kk] = 0.f;
    float ps = 0.f;
    __syncthreads();

    for (int ph = 0; ph < 2; ++ph) {      // two 64-channel slabs
        const int c0 = coff + ph * 64;
        float R[16], Rn[16];
#pragma unroll
        for (int i = 0; i < 16; ++i)
            R[i] = x[xbase + (size_t)(c0 + i) * HW_];
#pragma unroll
        for (int sub = 0; sub < 4; ++sub) {
            if (sub < 3) {
#pragma unroll
                for (int i = 0; i < 16; ++i)
                    Rn[i] = x[xbase + (size_t)(c0 + (sub + 1) * 16 + i) * HW_];
            }
#pragma unroll
            for (int i = 0; i < 16; ++i) {
                int cl = ph * 64 + sub * 16 + i;     // local channel 0..127
                float v = R[i];
                const float* ac = &aL[cl * 9];
#pragma unroll
                for (int kk = 0; kk < 9; ++kk) pg[kk] += ac[kk] * v;
                ps += v * v;
                tl[t][sub * 16 + i] = f2bf(v);
            }
            if (sub < 3) {
#pragma unroll
                for (int i = 0; i < 16; ++i) R[i] = Rn[i];
            }
        }
        __syncthreads();
        const int oct = t & 7;
#pragma unroll
        for (int pass = 0; pass < 8; ++pass) {
            int pxl = pass * 16 + (t >> 3);
            u16x8 v8 = *(const u16x8*)&tl[pxl][oct * 8];
            *(u16x8*)&xp[((size_t)(tile * PXB + pxl)) * C_ +
                         c0 + oct * 8] = v8;
        }
        __syncthreads();
    }

    // partial outputs: gp[half][kk][px], s2p[half][px]
    float* gh = gp + (size_t)half * 9 * NPIX;
#pragma unroll
    for (int kk = 0; kk < 9; ++kk) gh[(size_t)kk * NPIX + px] = pg[kk];
    s2p[(size_t)half * NPIX + px] = ps;
}

// ---- Kernel B2 (+A): vote -> histogram; 128 tail blocks do kbucket ----------
__global__ __launch_bounds__(256) void vote_kernel(const float* __restrict__ gp,
                                                   const float* __restrict__ s2p,
                                                   const float* __restrict__ ah,
                                                   const float* __restrict__ bh,
                                                   const float* __restrict__ kern,
                                                   int* __restrict__ counts,
                                                   int* __restrict__ kbuck) {
    int kb = blockIdx.x - NVB;
    if (kb >= 0) {
        int wv = threadIdx.x >> 6, lane = threadIdx.x & 63;
        int oc = kb * 4 + wv;
        const float* kr = kern + (size_t)oc * SPAN_;
        float dot = 0.f, ss = 0.f;
#pragma unroll
        for (int i = 0; i < 9; ++i) {
            float4 kv = *(const float4*)(kr + i * 256 + lane * 4);
            float4 av = *(const float4*)(ah + i * 256 + lane * 4);
            dot += kv.x * av.x + kv.y * av.y + kv.z * av.z + kv.w * av.w;
            ss  += kv.x * kv.x + kv.y * kv.y + kv.z * kv.z + kv.w * kv.w;
        }
#pragma unroll
        for (int off = 32; off; off >>= 1) {
            dot += __shfl_xor(dot, off);
            ss  += __shfl_xor(ss, off);
        }
        if (lane == 0) {
            float n2 = ss;            // ||k||^2
            float n4 = n2 * n2;
            float n8 = n4 * n4;
            float v = dot + n2 * ah[SPAN_] + n4 * ah[SPAN_ + 1] +
                      n8 * ah[SPAN_ + 2];
            kbuck[oc] = bucketf(v, bh[0]);
        }
        return;
    }

    __shared__ int hist[8];
    if (threadIdx.x < 8) hist[threadIdx.x] = 0;
    __syncthreads();
    int q = blockIdx.x * 256 + threadIdx.x;
    int n = q / HW_;
    int p = q - n * HW_;
    int h = p / W_;
    int w = p - h * W_;
    const float* g0 = gp;
    const float* g1 = gp + (size_t)9 * NPIX;
    float dot = 0.f, ss = 0.f;
#pragma unroll
    for (int kk = 0; kk < 9; ++kk) {
        int dh = kk / 3 - 1, dw = kk % 3 - 1;
        int hh = h + dh, ww = w + dw;
        if (hh >= 0 && hh < H_ && ww >= 0 && ww < W_) {
            int idx = n * HW_ + hh * W_ + ww;
            dot += g0[(size_t)kk * NPIX + idx] + g1[(size_t)kk * NPIX + idx];
            ss  += s2p[idx] + s2p[(size_t)NPIX + idx];
        }
    }
    float qext = 0.5f * (ah[SPAN_] + ah[SPAN_ + 1] + ah[SPAN_ + 2]);
    float v = dot / sqrtf(ss) + qext;
    int b = bucketf(v, bh[0]);
    atomicAdd(&hist[b], 1);
    __syncthreads();
    if (threadIdx.x < 8) atomicAdd(&counts[threadIdx.x], hist[threadIdx.x]);
}

// ---- Kernel P2: self-selecting weight fragmentation -------------------------
__global__ __launch_bounds__(256) void prep_w(const float* __restrict__ kern,
                                              const int* __restrict__ kbuck,
                                              const int* __restrict__ counts,
                                              const int* __restrict__ mode,
                                              float* __restrict__ out,
                                              u16* __restrict__ wfrag,
                                              int nfB, int oc_total) {
    __shared__ int sc[256];
    __shared__ int rowsL[512];
    int t = threadIdx.x;
    int best = 0, bc = counts[0];
#pragma unroll
    for (int i = 1; i < 8; ++i) {
        int c = counts[i];
        if (c > bc) { bc = c; best = i; }   // first max wins
    }
    int f0 = (kbuck[t] == best) ? 1 : 0;
    int f1 = (kbuck[t + 256] == best) ? 1 : 0;
    sc[t] = f0 | (f1 << 16);
    __syncthreads();
    for (int off = 1; off < 256; off <<= 1) {
        int add = (t >= off) ? sc[t - off] : 0;
        __syncthreads();
        sc[t] += add;
        __syncthreads();
    }
    int tot = sc[255];
    int t0  = tot & 0xffff;
    int cnt = t0 + (tot >> 16);
    int pos0 = (sc[t] & 0xffff) - f0;
    int pos1 = t0 + (sc[t] >> 16) - f1;
    rowsL[t] = 0; rowsL[t + 256] = 0;
    __syncthreads();
    if (cnt == 0) { rowsL[t] = t; rowsL[t + 256] = t + 256; }
    else {
        if (f0) rowsL[pos0] = t;
        if (f1) rowsL[pos1] = t + 256;
    }
    __syncthreads();
    int ocEff = (cnt == 0) ? OUTC : cnt;
    float scale = (mode[0] && cnt > 0) ? 512.0f / (float)cnt : 1.0f;

    if (blockIdx.x == 0) {                       // rows output (read as f32)
        float* rout = out + (size_t)N_ * oc_total * HW_;
        int nw = ocEff < oc_total ? ocEff : oc_total;
        if (cnt == 0) {
            if (t < nw) rout[t] = (float)t;
            if (t + 256 < nw) rout[t + 256] = (float)(t + 256);
        } else {
            if (f0 && pos0 < nw) rout[pos0] = (float)t;
            if (f1 && pos1 < nw) rout[pos1] = (float)(t + 256);
        }
    }

    // fragmentation: wfrag elem offset ((s*nfB + g)*64 + lane)*8, K = kk*256+c
    int e = blockIdx.x * 256 + t;
    int lane = e & 63;
    int t2 = e >> 6;
    int g = t2 % nfB;
    int s = t2 / nfB;                    // 0..71
    int kk = s >> 3;
    int cb = s & 7;
    int q = lane >> 4;
    int mcol = lane & 15;
    int oc_i = g * 16 + mcol;
    bool valid = oc_i < ocEff;
    int row = valid ? rowsL[oc_i] : 0;
    const float* kr = kern + (size_t)row * SPAN_;
    u16 w8[8];
#pragma unroll
    for (int j = 0; j < 8; ++j) {
        int c = cb * 32 + q * 8 + j;
        float v = valid ? kr[c * 9 + kk] * scale : 0.f;
        w8[j] = f2bf(v);
    }
    u16* dst = wfrag + ((size_t)((s * nfB + g) * 64 + lane)) * 8;
#pragma unroll
    for (int j = 0; j < 8; ++j) dst[j] = w8[j];
}

// ---- Kernel D: MFMA implicit-GEMM conv (round-9 version, measured 49.5) -----
// 4 waves/block, block tile 256 px x 48 oc. A staged via global_load_lds into a
// double-buffered quarter-XOR-swizzled LDS halo (1 barrier per 32-ch step,
// fully unrolled -> ds_read immediate offsets); invalid taps masked by cndmask;
// B register-pipelined one kk ahead, continuous across the cb seam.
__global__ __launch_bounds__(256, 2) void conv_mfma(const u16* __restrict__ xp,
                                                    const u16* __restrict__ wfrag,
                                                    float* __restrict__ out,
                                                    int nfB, int oc_total, int nby) {
    __shared__ char halo[2 * HBYTES];              // 49152 B

    // XCD swizzle: oc-sibling blocks co-located on one XCD; 196 bx = 24*8 + 4.
    int flat = blockIdx.x;
    int bx, by;
    int full = 192 * nby;
    if (flat < full) {
        int gsz = 8 * nby;
        int gi = flat / gsz;
        int tr = flat - gi * gsz;
        by = tr >> 3;
        bx = gi * 8 + (tr & 7);
    } else {
        int tr = flat - full;
        by = tr >> 2;
        bx = 192 + (tr & 3);
    }

    const int t = threadIdx.x;
    const int lane = t & 63;
    const int wv = t >> 6;                         // 0..3
    const int pb = bx * BLKPX;
    const int fb = by * 3;
    const int lane15 = lane & 15;
    const int laneq  = lane >> 4;

    // per-fragment validity masks (bit kk) + swizzled LDS read bases per dw.
    // base holds -3584 bias so the ds_read immediate (dh+1)*3584 stays >= 0.
    u32 valMask[4];
    int aB[4][3];
#pragma unroll
    for (int f = 0; f < 4; ++f) {
        int p = pb + wv * 64 + f * 16 + lane15;
        int img = p / HW_;
        int rp = p - img * HW_;
        int h = rp / W_;
        int w = rp - h * W_;
        u32 m = 0;
#pragma unroll
        for (int kk = 0; kk < 9; ++kk) {
            int dh = kk / 3 - 1, dw = kk % 3 - 1;
            int hh = h + dh, ww = w + dw;
            if (hh >= 0 && hh < H_ && ww >= 0 && ww < W_) m |= (1u << kk);
        }
        valMask[f] = m;
#pragma unroll
        for (int j = 0; j < 3; ++j) {               // dw = j-1
            int sn = 57 + wv * 64 + f * 16 + lane15 + (j - 1);
            aB[f][j] = sn * 64 + ((laneq ^ ((sn >> 1) & 3)) << 4) - 3584;
        }
    }

    f32x4 acc[4][3];
#pragma unroll
    for (int f = 0; f < 4; ++f)
#pragma unroll
        for (int gg = 0; gg < 3; ++gg) acc[f][gg] = (f32x4){0.f, 0.f, 0.f, 0.f};
    const bf16x8 zf = {0, 0, 0, 0, 0, 0, 0, 0};

    // staging: 6 global_load_lds_dwordx4/thread; LDS dest linear t*16;
    // global source quarter pre-swizzled: q' = (t&3) ^ ((t>>3)&3)
    const char* xpb = (const char*)xp;
    const int q4 = (((t & 3) ^ ((t >> 3) & 3)) << 4);
    int gpx[6];
#pragma unroll
    for (int r = 0; r < 6; ++r) {
        int p = pb - 57 + r * 64 + (t >> 2);
        gpx[r] = p < 0 ? 0 : (p >= NPIX ? NPIX - 1 : p);
    }

    // prologue: stage cb=0 into buf 0, load B(cb=0,kk=0)
#pragma unroll
    for (int r = 0; r < 6; ++r)
        __builtin_amdgcn_global_load_lds(
            (const __attribute__((address_space(1))) unsigned int*)
                (xpb + (size_t)gpx[r] * 512 + q4),
            (__attribute__((address_space(3))) unsigned int*)&halo[r * 4096 + t * 16],
            16, 0, 0);

    const size_t cbStride = (size_t)nfB * 512;
    const size_t kkStride = cbStride * 8;
    const u16* wl = wfrag + (size_t)fb * 512 + (size_t)lane * 8;
    bf16x8 bW[3], bWn[3];
#define LOADB(dst, cb_, kk_) do {                                               \
    const u16* _wp = wl + (size_t)(kk_) * kkStride + (size_t)(cb_) * cbStride;  \
    _Pragma("unroll")                                                           \
    for (int _g = 0; _g < 3; ++_g)                                              \
        dst[_g] = *(const bf16x8*)(_wp + (size_t)_g * 512);                     \
} while (0)

    LOADB(bW, 0, 0);

#pragma unroll
    for (int cb = 0; cb < 8; ++cb) {
        __syncthreads();                           // buf[cb&1] ready

        if (cb < 7) {                              // stage next cb, other buf
            const int nb = ((cb + 1) & 1) * HBYTES;
#pragma unroll
            for (int r = 0; r < 6; ++r)
                __builtin_amdgcn_global_load_lds(
                    (const __attribute__((address_space(1))) unsigned int*)
                        (xpb + (size_t)gpx[r] * 512 + (cb + 1) * 64 + q4),
                    (__attribute__((address_space(3))) unsigned int*)
                        &halo[nb + r * 4096 + t * 16],
                    16, 0, 0);
        }

#pragma unroll
        for (int kk = 0; kk < 9; ++kk) {
            // B prefetch distance 1, continuous across the cb seam
            if (kk < 8)       LOADB(bWn, cb, kk + 1);
            else if (cb < 7)  LOADB(bWn, cb + 1, 0);

            const int dh = kk / 3 - 1;
            const int j  = kk % 3;                 // dw + 1
            const int IMM = (cb & 1) * HBYTES + (dh + 1) * 3584;  // compile-time
            bf16x8 aX[4];
#pragma unroll
            for (int f = 0; f < 4; ++f) {
                bf16x8 a = *(const bf16x8*)&halo[aB[f][j] + IMM];
                aX[f] = ((valMask[f] >> kk) & 1) ? a : zf;
            }
#pragma unroll
            for (int gg = 0; gg < 3; ++gg)
#pragma unroll
                for (int f = 0; f < 4; ++f)
                    acc[f][gg] = __builtin_amdgcn_mfma_f32_16x16x32_bf16(
                        aX[f], bW[gg], acc[f][gg], 0, 0, 0);
            if (kk < 8 || cb < 7) {
#pragma unroll
                for (int gg = 0; gg < 3; ++gg) bW[gg] = bWn[gg];
            }
        }
    }
#undef LOADB

    // epilogue: D row (pixel) = (lane>>4)*4 + r, col (oc) = lane&15
#pragma unroll
    for (int f = 0; f < 4; ++f) {
        int p0 = pb + wv * 64 + f * 16 + laneq * 4;
        int img0 = p0 / HW_;
        int hw0 = p0 - img0 * HW_;
#pragma unroll
        for (int gg = 0; gg < 3; ++gg) {
            int oc = (fb + gg) * 16 + lane15;
            if (oc < oc_total) {
                float* op = out + ((size_t)img0 * oc_total + oc) * HW_ + hw0;
                *(f32x4*)op = acc[f][gg];
            }
        }
    }
}

extern "C" void kernel_launch(void* const* d_in, const int* in_sizes, int n_in,
                              void* d_out, int out_size, void* d_ws, size_t ws_size,
                              hipStream_t stream) {
    const float* x    = (const float*)d_in[0];
    const float* kern = (const float*)d_in[1];
    const float* ah   = (const float*)d_in[2];
    const float* bh   = (const float*)d_in[3];
    const int*   mode = (const int*)d_in[4];
    float* out = (float*)d_out;

    // oc is data-dependent but recoverable from out_size: oc*(16*3136+1)
    int oc_total = (out_size % (N_ * HW_ + 1) == 0) ? out_size / (N_ * HW_ + 1)
                                                    : OUTC;
    int nfTot = (oc_total + 15) / 16;
    int nby   = (nfTot + 2) / 3;             // 3 fragments (48 oc) per block
    int nfB   = nby * 3;

    // workspace layout. gparts (prep2h/vote lifetime) and wfrag (prep_w/conv
    // lifetime) are disjoint in time -> OVERLAY them to stay in the proven
    // ws envelope. Total: 25.7 + 4.0 MB + 2 KB.
    u16*   xp     = (u16*)d_ws;                                  // NPIX*C_ u16
    float* scratch = (float*)(xp + (size_t)NPIX * C_);
    float* gp     = scratch;                                     // 18*NPIX f32
    float* s2p    = scratch + (size_t)18 * NPIX;                 // 2*NPIX f32
    u16*   wfrag  = (u16*)scratch;                               // overlay
    int*   counts = (int*)(scratch + (size_t)20 * NPIX);         // 8
    int*   kbuck  = counts + 8;                                  // 512

    hipMemsetAsync(counts, 0, 8 * sizeof(int), stream);

    prep2h<<<NPB2, 128, 0, stream>>>(x, ah, xp, gp, s2p);
    vote_kernel<<<NVB + 128, 256, 0, stream>>>(gp, s2p, ah, bh, kern, counts,
                                               kbuck);
    prep_w<<<18 * nfB, 256, 0, stream>>>(kern, kbuck, counts, mode, out, wfrag,
                                         nfB, oc_total);
    conv_mfma<<<(NPIX / BLKPX) * nby, 256, 0, stream>>>(xp, wfrag, out, nfB,
                                                        oc_total, nby);
}